// Round 1
// baseline (69.874 us; speedup 1.0000x reference)
//
#include <hip/hip_runtime.h>
#include <math.h>

#define BLOCK 256
#define IPB 4   // i's per block

#define PI_F      3.14159265358979323846f
#define TAU_F     6.2831853071795864769f
#define INV_TAU_F 0.15915494309189533577f
// cutoff: dist <= phi^2  <=>  r2 <= phi^4
#define PHI4_F    6.854101966249685f

extern "C" __device__ float __builtin_amdgcn_rsqf(float);

// Kernel A: one-shot precompute of {x, y, ell, theta} per point into d_ws.
// Removes all exp/sincos from the O(N^2) hot loop (previously recomputed
// 1024x redundantly, once per block, at the head of every j-iteration's
// dependent chain).
__global__ __launch_bounds__(256) void precompute_xy(
        const float* __restrict__ ell,
        const float* __restrict__ theta,
        float4* __restrict__ P, int n) {
    int j = blockIdx.x * 256 + threadIdx.x;
    if (j < n) {
        float e  = ell[j];
        float th = theta[j];
        float lam = __expf(e);
        float sn, cs;
        __sincosf(th, &sn, &cs);
        P[j] = make_float4(lam * cs, lam * sn, e, th);
    }
}

// Kernel B: all-pairs repulsion. Block b owns rows i0..i0+3 (i-data from
// uniform s_load_dwordx4 of P). Thread t strides j = t, t+256, ... loading
// one float4 + one dword per j; inner loop is pure full-rate VALU + one
// v_rsq per pair. Self-pair masked via r2 > 0. Register accumulators ->
// wave butterfly -> LDS cross-wave -> direct stores (every out element
// written exactly once; no atomics, no pre-zeroing).
__global__ __launch_bounds__(BLOCK) void repulse_main(
        const float4* __restrict__ P,
        const float* __restrict__ s,
        const unsigned char* __restrict__ frozen,
        float* __restrict__ out, int n) {
    const int t  = threadIdx.x;
    const int i0 = blockIdx.x * IPB;

    float xi[IPB], yi[IPB], eli[IPB], api[IPB];
#pragma unroll
    for (int v = 0; v < IPB; ++v) {
        float4 pi = P[i0 + v];          // uniform -> s_load_dwordx4
        xi[v]  = pi.x;
        yi[v]  = pi.y;
        eli[v] = pi.z;
        api[v] = PI_F - pi.w;           // dth arg = theta_j + (pi - theta_i)
    }

    float Fe[IPB], Ft[IPB];
#pragma unroll
    for (int v = 0; v < IPB; ++v) { Fe[v] = 0.0f; Ft[v] = 0.0f; }

#pragma unroll 4
    for (int j = t; j < n; j += BLOCK) {
        float4 p  = P[j];               // {x_j, y_j, ell_j, theta_j}
        float  sj = s[j];
#pragma unroll
        for (int v = 0; v < IPB; ++v) {
            float dx = p.x - xi[v];
            float dy = p.y - yi[v];
            float r2 = fmaf(dx, dx, dy * dy);
            float rinv = __builtin_amdgcn_rsqf(r2);     // rsq(0)=inf, masked below
            bool ok = (r2 <= PHI4_F) && (r2 > 0.0f);    // cutoff + diagonal
            float f = ok ? sj * rinv : 0.0f;            // s_j/dist (s_i in epilogue)
            float tt = p.w + api[v];                    // theta_j - theta_i + pi
            float dth = fmaf(-floorf(tt * INV_TAU_F), TAU_F, tt) - PI_F;
            Fe[v] = fmaf(f, p.z - eli[v], Fe[v]);
            Ft[v] = fmaf(f, dth, Ft[v]);
        }
    }

    // wave-level butterfly reduction (wave = 64 lanes)
#pragma unroll
    for (int v = 0; v < IPB; ++v) {
#pragma unroll
        for (int off = 32; off >= 1; off >>= 1) {
            Fe[v] += __shfl_xor(Fe[v], off, 64);
            Ft[v] += __shfl_xor(Ft[v], off, 64);
        }
    }

    __shared__ float red[(BLOCK / 64) * IPB * 2];   // [wave][v][e/t]
    const int wave = t >> 6;
    const int lane = t & 63;
    if (lane == 0) {
#pragma unroll
        for (int v = 0; v < IPB; ++v) {
            red[wave * IPB * 2 + v * 2 + 0] = Fe[v];
            red[wave * IPB * 2 + v * 2 + 1] = Ft[v];
        }
    }
    __syncthreads();

    // threads 0..IPB*2-1: sum across waves, apply s_i & frozen, store
    if (t < IPB * 2) {
        int v = t >> 1;
        int c = t & 1;        // 0 = F_ell, 1 = F_theta
        float sum = 0.0f;
#pragma unroll
        for (int w = 0; w < BLOCK / 64; ++w)
            sum += red[w * IPB * 2 + v * 2 + c];
        int i = i0 + v;
        float val = frozen[i] ? 0.0f : s[i] * sum;
        out[c * n + i] = val;
    }
}

extern "C" void kernel_launch(void* const* d_in, const int* in_sizes, int n_in,
                              void* d_out, int out_size, void* d_ws, size_t ws_size,
                              hipStream_t stream) {
    const float* ell   = (const float*)d_in[0];
    const float* theta = (const float*)d_in[1];
    const float* s     = (const float*)d_in[2];
    const unsigned char* frozen = (const unsigned char*)d_in[3];
    float* out = (float*)d_out;
    int n = in_sizes[0];

    float4* P = (float4*)d_ws;

    precompute_xy<<<(n + 255) / 256, 256, 0, stream>>>(ell, theta, P, n);

    int grid = (n + IPB - 1) / IPB;   // 1024 blocks; every out element written once
    repulse_main<<<grid, BLOCK, 0, stream>>>(P, s, frozen, out, n);
}

// Round 2
// 68.515 us; speedup vs baseline: 1.0198x; 1.0198x over previous
//
#include <hip/hip_runtime.h>
#include <math.h>

#define BLOCK 256
#define IPB 4   // i's per block

#define PI_F      3.14159265358979323846f
#define TAU_F     6.2831853071795864769f
#define INV_TAU_F 0.15915494309189533577f
// cutoff: dist <= phi^2  <=>  r2 <= phi^4
#define PHI4_F    6.854101966249685f

extern "C" __device__ float __builtin_amdgcn_rsqf(float);

// Single fused kernel (REVERT of the two-launch split: round-1 evidence
// showed the split's kernel saving (~0.3 us: each thread only does 16
// exp+sincos, reused across 4 i's) is smaller than one extra launch (~1 us).
// Block b owns rows i0..i0+3; thread t strides j = t, t+256, ... over all
// points, recomputing x_j,y_j on the fly. Self-pair masked via r2 > 0.
// Register accumulators -> wave butterfly -> LDS cross-wave -> direct
// stores (every out element written exactly once; no atomics, no
// pre-zeroing, no workspace -> no extra launches, no d_ws dependency).
__global__ __launch_bounds__(BLOCK) void repulse_fused(
        const float* __restrict__ ell,
        const float* __restrict__ theta,
        const float* __restrict__ s,
        const unsigned char* __restrict__ frozen,
        float* __restrict__ out, int n) {
    const int t  = threadIdx.x;
    const int i0 = blockIdx.x * IPB;

    float xi[IPB], yi[IPB], eli[IPB], api[IPB];
#pragma unroll
    for (int v = 0; v < IPB; ++v) {
        int i = i0 + v;                 // uniform -> s_load
        float e  = ell[i];
        float th = theta[i];
        float lam = __expf(e);
        float sn, cs;
        __sincosf(th, &sn, &cs);
        xi[v] = lam * cs; yi[v] = lam * sn;
        eli[v] = e;
        api[v] = PI_F - th;             // dth arg = theta_j + (pi - theta_i)
    }

    float Fe[IPB], Ft[IPB];
#pragma unroll
    for (int v = 0; v < IPB; ++v) { Fe[v] = 0.0f; Ft[v] = 0.0f; }

#pragma unroll 8
    for (int j = t; j < n; j += BLOCK) {
        float e  = ell[j];
        float th = theta[j];
        float sj = s[j];
        float lam = __expf(e);
        float sn, cs;
        __sincosf(th, &sn, &cs);
        float bx = lam * cs, by = lam * sn;
#pragma unroll
        for (int v = 0; v < IPB; ++v) {
            float dx = bx - xi[v];
            float dy = by - yi[v];
            float r2 = fmaf(dx, dx, dy * dy);
            float rinv = __builtin_amdgcn_rsqf(r2);     // rsq(0)=inf, masked below
            bool ok = (r2 <= PHI4_F) && (r2 > 0.0f);    // cutoff + diagonal
            float f = ok ? sj * rinv : 0.0f;            // s_j/dist (s_i in epilogue)
            float tt = th + api[v];                     // theta_j - theta_i + pi
            float dth = fmaf(-floorf(tt * INV_TAU_F), TAU_F, tt) - PI_F;
            Fe[v] = fmaf(f, e - eli[v], Fe[v]);
            Ft[v] = fmaf(f, dth, Ft[v]);
        }
    }

    // wave-level butterfly reduction (wave = 64 lanes)
#pragma unroll
    for (int v = 0; v < IPB; ++v) {
#pragma unroll
        for (int off = 32; off >= 1; off >>= 1) {
            Fe[v] += __shfl_xor(Fe[v], off, 64);
            Ft[v] += __shfl_xor(Ft[v], off, 64);
        }
    }

    __shared__ float red[(BLOCK / 64) * IPB * 2];   // [wave][v][e/t]
    const int wave = t >> 6;
    const int lane = t & 63;
    if (lane == 0) {
#pragma unroll
        for (int v = 0; v < IPB; ++v) {
            red[wave * IPB * 2 + v * 2 + 0] = Fe[v];
            red[wave * IPB * 2 + v * 2 + 1] = Ft[v];
        }
    }
    __syncthreads();

    // threads 0..IPB*2-1: sum across waves, apply s_i & frozen, store
    if (t < IPB * 2) {
        int v = t >> 1;
        int c = t & 1;        // 0 = F_ell, 1 = F_theta
        float sum = 0.0f;
#pragma unroll
        for (int w = 0; w < BLOCK / 64; ++w)
            sum += red[w * IPB * 2 + v * 2 + c];
        int i = i0 + v;
        float val = frozen[i] ? 0.0f : s[i] * sum;
        out[c * n + i] = val;
    }
}

extern "C" void kernel_launch(void* const* d_in, const int* in_sizes, int n_in,
                              void* d_out, int out_size, void* d_ws, size_t ws_size,
                              hipStream_t stream) {
    const float* ell   = (const float*)d_in[0];
    const float* theta = (const float*)d_in[1];
    const float* s     = (const float*)d_in[2];
    const unsigned char* frozen = (const unsigned char*)d_in[3];
    float* out = (float*)d_out;
    int n = in_sizes[0];

    int grid = (n + IPB - 1) / IPB;   // 1024 blocks; every out element written once
    repulse_fused<<<grid, BLOCK, 0, stream>>>(ell, theta, s, frozen, out, n);
}